// Round 10
// baseline (427.403 us; speedup 1.0000x reference)
//
#include <hip/hip_runtime.h>
#include <hip/hip_bf16.h>

#define NL 32768L

typedef __bf16 bf16x8 __attribute__((ext_vector_type(8)));
typedef float f32x16 __attribute__((ext_vector_type(16)));
typedef float f32x3 __attribute__((ext_vector_type(3)));
typedef float f32x4v __attribute__((ext_vector_type(4)));

__device__ __forceinline__ unsigned short f2bf(float f) {
  unsigned int u = __float_as_uint(f);
  u += 0x7FFFu + ((u >> 16) & 1u);   // round-to-nearest-even
  return (unsigned short)(u >> 16);
}

__device__ __forceinline__ float frcp(float x) {
  float r;
  asm("v_rcp_f32 %0, %1" : "=v"(r) : "v"(x));
  return r;
}

__device__ __forceinline__ void gload16(const void* g, void* l) {
  __builtin_amdgcn_global_load_lds((const __attribute__((address_space(1))) void*)g,
                                   (__attribute__((address_space(3))) void*)l, 16, 0, 0);
}

__device__ __forceinline__ void vmwait0() {
  asm volatile("s_waitcnt vmcnt(0)" ::: "memory");
}

// ---- combined prep: x -> bf16 d-major planes, weights -> transposed bf16 ----
__global__ void prep_kernel(const float* __restrict__ x,
                            const float* __restrict__ w1_0, const float* __restrict__ w1_1,
                            const float* __restrict__ w1_2, const float* __restrict__ w2_0,
                            const float* __restrict__ w2_1, const float* __restrict__ w2_2,
                            unsigned short* __restrict__ Xp, unsigned short* __restrict__ W) {
  long i = (long)blockIdx.x * blockDim.x + threadIdx.x;
  if (i < NL * 512) {
    long n = i >> 9, u = i & 511;
    Xp[i] = f2bf(x[n * 1920 + u]);
  } else if (i < NL * 768) {
    long j = i - NL * 512;
    long n = j >> 8, u = j & 255;
    const float* s = x + n * 1920 + 512 + u * 3;
    unsigned short* d = Xp + NL * 512 + n * 256 + u;
    d[0]        = f2bf(s[0]);
    d[NL * 256] = f2bf(s[1]);
    d[NL * 512] = f2bf(s[2]);
  } else if (i < NL * 896) {
    long j = i - NL * 768;
    long n = j >> 7, u = j & 127;
    const float* s = x + n * 1920 + 1280 + u * 5;
    unsigned short* d = Xp + NL * 1280 + n * 128 + u;
#pragma unroll
    for (int k = 0; k < 5; ++k) d[k * NL * 128] = f2bf(s[k]);
  } else {
    long j = i - NL * 896;
    if (j < 524288) {            // w1_0: K=512, C=1024
      int c = (int)(j >> 9), r = (int)(j & 511);
      W[j] = f2bf(w1_0[(long)r * 1024 + c]);
    } else if (j < 655360) {     // w1_1: K=256, C=512
      long t = j - 524288; int c = (int)(t >> 8), r = (int)(t & 255);
      W[j] = f2bf(w1_1[(long)r * 512 + c]);
    } else if (j < 688128) {     // w1_2: K=128, C=256
      long t = j - 655360; int c = (int)(t >> 7), r = (int)(t & 127);
      W[j] = f2bf(w1_2[(long)r * 256 + c]);
    } else if (j < 1212416) {    // w2_0: K=1024, C=512
      long t = j - 688128; int c = (int)(t >> 10), r = (int)(t & 1023);
      W[j] = f2bf(w2_0[(long)r * 512 + c]);
    } else if (j < 1343488) {    // w2_1: K=512, C=256
      long t = j - 1212416; int c = (int)(t >> 9), r = (int)(t & 511);
      W[j] = f2bf(w2_1[(long)r * 256 + c]);
    } else if (j < 1376256) {    // w2_2: K=256, C=128
      long t = j - 1343488; int c = (int)(t >> 8), r = (int)(t & 255);
      W[j] = f2bf(w2_2[(long)r * 128 + c]);
    }
  }
}

// ---- GEMM core: 256 thr, 4 waves 2x2, 32x32x16 MFMA, templated BK ----------
// BK=64 -> 128B LDS rows + rank-8 slot-XOR = zero bank conflicts (r6 PMC).
// Schedule: stage(t+1) BEFORE compute(t); one vmcnt(0)+barrier per substep.
// 64KB dbuf -> 2 blocks/CU (block TLP hides drain).
// MODE 0: normact across P planes -> bf16 planes.  MODE 1: f32 interleaved out.
template <int P, int BM, int BN, int K, int NN, int MODE, int BK>
__device__ __forceinline__ void gemm_core(
    unsigned short* sm, int b,
    const unsigned short* __restrict__ Ap, long planeA,
    const unsigned short* __restrict__ Wt,
    void* __restrict__ outp, long planeOut, int outOff, float sc) {
  constexpr int SLOTS = BK / 8;                // 16B chunks per row
  constexpr int SWM = SLOTS - 1;               // swizzle mask
  constexpr int KS = BK / 16;                  // MFMA k-steps per substep
  constexpr int RM = BM / 2, RN = BN / 2;
  constexpr int FM = RM / 32, FN = RN / 32;
  constexpr int CHA = P * BM * SLOTS, CHB = BN * SLOTS, TCH = CHA + CHB;
  constexpr int ITER = TCH / 256;
  static_assert(TCH % 256 == 0 && CHA % 256 == 0, "uniform staging");
  constexpr int ABUF = P * BM * BK;            // elems
  constexpr int BUFE = ABUF + BN * BK;
  constexpr int NT = K / BK;
  constexpr int NX = NN / BN;
  constexpr int NWG = (32768 / BM) * NX;
  static_assert(NWG % 8 == 0, "XCD swizzle");

  const int tid = threadIdx.x;
  const int lane = tid & 63, wv = tid >> 6;
  const int wr = wv >> 1, wc = wv & 1;
  const int ln31 = lane & 31, kh = lane >> 5;

  const int wg = (b & 7) * (NWG / 8) + (b >> 3);   // bijective XCD swizzle
  const long m0 = (long)(wg / NX) * BM;
  const int n0 = (wg % NX) * BN;

  f32x16 acc[P][FM][FN];
#pragma unroll
  for (int p = 0; p < P; ++p)
#pragma unroll
    for (int a = 0; a < FM; ++a)
#pragma unroll
      for (int c = 0; c < FN; ++c) acc[p][a][c] = (f32x16)0.f;

  auto stage = [&](unsigned short* buf, int t) {
#pragma unroll
    for (int it = 0; it < ITER; ++it) {
      int c = it * 256 + tid;
      if ((it + 1) * 256 <= CHA) {           // compile-time split per unrolled it
        int p = c / (BM * SLOTS);
        int cp = c - p * (BM * SLOTS);
        int row = cp / SLOTS, sl = cp & SWM;
        int slp = sl ^ ((row >> 1) & SWM);
        gload16(Ap + (long)p * planeA + (m0 + row) * K + t * BK + slp * 8, buf + c * 8);
      } else {
        int cb = c - CHA;
        int row = cb / SLOTS, sl = cb & SWM;
        int slp = sl ^ ((row >> 1) & SWM);
        gload16(Wt + (long)(n0 + row) * K + t * BK + slp * 8, buf + ABUF + cb * 8);
      }
    }
  };

  auto compute = [&](const unsigned short* buf) {
#pragma unroll
    for (int ks = 0; ks < KS; ++ks) {
      bf16x8 bv[FN];
#pragma unroll
      for (int fn = 0; fn < FN; ++fn) {
        int row = wc * RN + fn * 32 + ln31;
        int s = (ks * 2 + kh) ^ ((row >> 1) & SWM);
        bv[fn] = *(const bf16x8*)(buf + ABUF + row * BK + s * 8);
      }
      bf16x8 av[P][FM];
#pragma unroll
      for (int p = 0; p < P; ++p)
#pragma unroll
        for (int fm = 0; fm < FM; ++fm) {
          int row = wr * RM + fm * 32 + ln31;
          int s = (ks * 2 + kh) ^ ((row >> 1) & SWM);
          av[p][fm] = *(const bf16x8*)(buf + p * BM * BK + row * BK + s * 8);
        }
      __builtin_amdgcn_s_setprio(1);
#pragma unroll
      for (int p = 0; p < P; ++p)
#pragma unroll
        for (int fm = 0; fm < FM; ++fm)
#pragma unroll
          for (int fn = 0; fn < FN; ++fn)
            acc[p][fm][fn] = __builtin_amdgcn_mfma_f32_32x32x16_bf16(
                av[p][fm], bv[fn], acc[p][fm][fn], 0, 0, 0);
      __builtin_amdgcn_s_setprio(0);
    }
  };

  stage(sm, 0);
  vmwait0();
  __builtin_amdgcn_s_barrier();
  asm volatile("" ::: "memory");
#pragma unroll
  for (int t = 0; t < NT; ++t) {
    if (t + 1 < NT) stage(sm + ((t + 1) & 1) * BUFE, t + 1);
    compute(sm + (t & 1) * BUFE);
    if (t + 1 < NT) {
      vmwait0();
      __builtin_amdgcn_s_barrier();
      asm volatile("" ::: "memory");
    }
  }

  if constexpr (MODE == 0) {
    __hip_bfloat16* H = (__hip_bfloat16*)outp;
#pragma unroll
    for (int fm = 0; fm < FM; ++fm)
#pragma unroll
      for (int fn = 0; fn < FN; ++fn)
#pragma unroll
        for (int reg = 0; reg < 16; ++reg) {
          long row = m0 + wr * RM + fm * 32 + (reg & 3) + 8 * (reg >> 2) + 4 * kh;
          int col = n0 + wc * RN + fn * 32 + ln31;
          float vs[P];
          float n2 = 0.f;
#pragma unroll
          for (int p = 0; p < P; ++p) {
            float v = acc[p][fm][fn][reg] * sc;
            vs[p] = v;
            n2 += v * v;
          }
          float nm = (P == 1) ? fabsf(vs[0]) : sqrtf(n2);
          float sg = frcp(1.f + __expf(-nm));   // silu(n)/n == sigmoid(n)
#pragma unroll
          for (int p = 0; p < P; ++p)
            H[p * planeOut + row * NN + col] = __float2bfloat16(vs[p] * sg);
        }
  } else {
    float* O = (float*)outp;
#pragma unroll
    for (int fm = 0; fm < FM; ++fm)
#pragma unroll
      for (int fn = 0; fn < FN; ++fn)
#pragma unroll
        for (int reg = 0; reg < 16; ++reg) {
          long row = m0 + wr * RM + fm * 32 + (reg & 3) + 8 * (reg >> 2) + 4 * kh;
          int col = n0 + wc * RN + fn * 32 + ln31;
          float* base = O + row * 1920 + outOff + (long)col * P;
          if constexpr (P == 1) {
            base[0] = acc[0][fm][fn][reg] * sc;
          } else if constexpr (P == 3) {
            f32x3 v3;
#pragma unroll
            for (int p = 0; p < 3; ++p) v3[p] = acc[p][fm][fn][reg] * sc;
            *(f32x3*)base = v3;
          } else {
            f32x4v v4;
#pragma unroll
            for (int p = 0; p < 4; ++p) v4[p] = acc[p][fm][fn][reg] * sc;
            *(f32x4v*)base = v4;
            base[4] = acc[4][fm][fn][reg] * sc;
          }
        }
  }
}

// ---- dispatches: 4 GEMM kernels (l0 separate for attribution), 64KB LDS ----
__global__ __launch_bounds__(256, 2) void g1a_kernel(
    const unsigned short* __restrict__ Xp, const unsigned short* __restrict__ W,
    unsigned short* __restrict__ Hp) {
  extern __shared__ unsigned short sm[];
  gemm_core<1, 128, 128, 512, 1024, 0, 64>(sm, blockIdx.x, Xp, 0, W, Hp, 0, 0,
                                           0.04419417382f);
}

__global__ __launch_bounds__(256, 2) void g1b_kernel(
    const unsigned short* __restrict__ Xp, const unsigned short* __restrict__ W,
    unsigned short* __restrict__ Hp) {
  extern __shared__ unsigned short sm[];
  int b = blockIdx.x;
  if (b < 4096) {        // l1: P=3, 64x64, K=256, BK=64
    gemm_core<3, 64, 64, 256, 512, 0, 64>(sm, b, Xp + NL * 512, NL * 256, W + 524288,
                                          Hp + NL * 1024, NL * 512, 0, 0.0625f);
  } else {               // l2: P=5, 64x64, K=128, BK=32
    gemm_core<5, 64, 64, 128, 256, 0, 32>(sm, b - 4096, Xp + NL * 1280, NL * 128, W + 655360,
                                          Hp + NL * 2560, NL * 256, 0, 0.08838834765f);
  }
}

__global__ __launch_bounds__(256, 2) void g2a_kernel(
    const unsigned short* __restrict__ Hp, const unsigned short* __restrict__ W,
    float* __restrict__ out) {
  extern __shared__ unsigned short sm[];
  gemm_core<1, 128, 128, 1024, 512, 1, 64>(sm, blockIdx.x, Hp, 0, W + 688128, out, 0, 0,
                                           0.03125f);
}

__global__ __launch_bounds__(256, 2) void g2b_kernel(
    const unsigned short* __restrict__ Hp, const unsigned short* __restrict__ W,
    float* __restrict__ out) {
  extern __shared__ unsigned short sm[];
  int b = blockIdx.x;
  if (b < 2048) {        // l1: P=3, 64x64, K=512, BK=64
    gemm_core<3, 64, 64, 512, 256, 1, 64>(sm, b, Hp + NL * 1024, NL * 512, W + 1212416,
                                          out, 0, 512, 0.04419417382f);
  } else {               // l2: P=5, 64x64, K=256, BK=32
    gemm_core<5, 64, 64, 256, 128, 1, 32>(sm, b - 2048, Hp + NL * 2560, NL * 256, W + 1343488,
                                          out, 0, 1280, 0.0625f);
  }
}

extern "C" void kernel_launch(void* const* d_in, const int* in_sizes, int n_in,
                              void* d_out, int out_size, void* d_ws, size_t ws_size,
                              hipStream_t stream) {
  const float* x = (const float*)d_in[0];
  const float* w1_0 = (const float*)d_in[1];
  const float* w1_1 = (const float*)d_in[2];
  const float* w1_2 = (const float*)d_in[3];
  const float* w2_0 = (const float*)d_in[4];
  const float* w2_1 = (const float*)d_in[5];
  const float* w2_2 = (const float*)d_in[6];
  float* out = (float*)d_out;

  unsigned short* Xp = (unsigned short*)d_ws;      // N*1920 bf16
  unsigned short* Hp = Xp + NL * 1920;             // N*3840 bf16
  unsigned short* W  = Hp + NL * 3840;             // 1376256 bf16 (all Wt blocks)

  {
    long total = NL * 896 + 1376256;
    prep_kernel<<<dim3((unsigned)((total + 255) / 256)), dim3(256), 0, stream>>>(
        x, w1_0, w1_1, w1_2, w2_0, w2_1, w2_2, Xp, W);
  }

  g1a_kernel<<<2048, 256, 65536, stream>>>(Xp, W, Hp);
  g1b_kernel<<<6144, 256, 65536, stream>>>(Xp, W, Hp);
  g2a_kernel<<<1024, 256, 65536, stream>>>(Hp, W, out);
  g2b_kernel<<<3072, 256, 65536, stream>>>(Hp, W, out);
}

// Round 12
// 415.690 us; speedup vs baseline: 1.0282x; 1.0282x over previous
//
#include <hip/hip_runtime.h>
#include <hip/hip_bf16.h>

#define NL 32768L

typedef __bf16 bf16x8 __attribute__((ext_vector_type(8)));
typedef float f32x16 __attribute__((ext_vector_type(16)));
typedef float f32x3 __attribute__((ext_vector_type(3)));
typedef float f32x4v __attribute__((ext_vector_type(4)));

__device__ __forceinline__ unsigned short f2bf(float f) {
  unsigned int u = __float_as_uint(f);
  u += 0x7FFFu + ((u >> 16) & 1u);   // round-to-nearest-even
  return (unsigned short)(u >> 16);
}

__device__ __forceinline__ float frcp(float x) {
  float r;
  asm("v_rcp_f32 %0, %1" : "=v"(r) : "v"(x));
  return r;
}

__device__ __forceinline__ void gload16(const void* g, void* l) {
  __builtin_amdgcn_global_load_lds((const __attribute__((address_space(1))) void*)g,
                                   (__attribute__((address_space(3))) void*)l, 16, 0, 0);
}

template <int N>
__device__ __forceinline__ void vmwait() {
  if constexpr (N == 0) asm volatile("s_waitcnt vmcnt(0)" ::: "memory");
  else if constexpr (N == 4) asm volatile("s_waitcnt vmcnt(4)" ::: "memory");
  else if constexpr (N == 8) asm volatile("s_waitcnt vmcnt(8)" ::: "memory");
  else static_assert(N == 0, "unsupported vmcnt");
}

__device__ __forceinline__ void vmwait0() {
  asm volatile("s_waitcnt vmcnt(0)" ::: "memory");
}

// ---- combined prep: x -> bf16 d-major planes, weights -> transposed bf16 ----
__global__ void prep_kernel(const float* __restrict__ x,
                            const float* __restrict__ w1_0, const float* __restrict__ w1_1,
                            const float* __restrict__ w1_2, const float* __restrict__ w2_0,
                            const float* __restrict__ w2_1, const float* __restrict__ w2_2,
                            unsigned short* __restrict__ Xp, unsigned short* __restrict__ W) {
  long i = (long)blockIdx.x * blockDim.x + threadIdx.x;
  if (i < NL * 512) {
    long n = i >> 9, u = i & 511;
    Xp[i] = f2bf(x[n * 1920 + u]);
  } else if (i < NL * 768) {
    long j = i - NL * 512;
    long n = j >> 8, u = j & 255;
    const float* s = x + n * 1920 + 512 + u * 3;
    unsigned short* d = Xp + NL * 512 + n * 256 + u;
    d[0]        = f2bf(s[0]);
    d[NL * 256] = f2bf(s[1]);
    d[NL * 512] = f2bf(s[2]);
  } else if (i < NL * 896) {
    long j = i - NL * 768;
    long n = j >> 7, u = j & 127;
    const float* s = x + n * 1920 + 1280 + u * 5;
    unsigned short* d = Xp + NL * 1280 + n * 128 + u;
#pragma unroll
    for (int k = 0; k < 5; ++k) d[k * NL * 128] = f2bf(s[k]);
  } else {
    long j = i - NL * 896;
    if (j < 524288) {            // w1_0: K=512, C=1024
      int c = (int)(j >> 9), r = (int)(j & 511);
      W[j] = f2bf(w1_0[(long)r * 1024 + c]);
    } else if (j < 655360) {     // w1_1: K=256, C=512
      long t = j - 524288; int c = (int)(t >> 8), r = (int)(t & 255);
      W[j] = f2bf(w1_1[(long)r * 512 + c]);
    } else if (j < 688128) {     // w1_2: K=128, C=256
      long t = j - 655360; int c = (int)(t >> 7), r = (int)(t & 127);
      W[j] = f2bf(w1_2[(long)r * 256 + c]);
    } else if (j < 1212416) {    // w2_0: K=1024, C=512
      long t = j - 688128; int c = (int)(t >> 10), r = (int)(t & 1023);
      W[j] = f2bf(w2_0[(long)r * 512 + c]);
    } else if (j < 1343488) {    // w2_1: K=512, C=256
      long t = j - 1212416; int c = (int)(t >> 9), r = (int)(t & 511);
      W[j] = f2bf(w2_1[(long)r * 256 + c]);
    } else if (j < 1376256) {    // w2_2: K=256, C=128
      long t = j - 1343488; int c = (int)(t >> 8), r = (int)(t & 255);
      W[j] = f2bf(w2_2[(long)r * 128 + c]);
    }
  }
}

// ---- gemm0: l0 GEMM, 512 thr, 8 waves 2x4, per-wave 128x64, depth-3 --------
// BM=BN=256, BK=32 substeps, 4 LDS buffers (32KB each), counted vmcnt:
// steady {vmwait(8); barrier; stage(t+3); compute(t)} -- 2 substeps always in
// flight across barriers (m201 mechanism). Race-free: stage(t+3) writes
// buf[(t-1)&3], last read in phase t-1, barrier between.
// NCOL: output columns (tile decomposition). OSTRIDE: output row stride.
// MODE 0: normact -> bf16 H[row*OSTRIDE+col].  MODE 1: f32 O[row*OSTRIDE+col].
template <int K, int NCOL, int OSTRIDE, int MODE>
__global__ __launch_bounds__(512, 2) void gemm0(
    const unsigned short* __restrict__ Ap, const unsigned short* __restrict__ Wt,
    void* __restrict__ outp, float sc) {
  constexpr int NT = K / 32;
  constexpr int NX = NCOL / 256;
  constexpr int NWG = 128 * NX;
  static_assert(NCOL % 256 == 0 && NWG % 8 == 0, "tile decomposition");
  extern __shared__ unsigned short sm[];

  const int tid = threadIdx.x;
  const int lane = tid & 63, wv = tid >> 6;
  const int wr = wv >> 2, wc = wv & 3;        // 2x4 wave grid
  const int ln31 = lane & 31, kh = lane >> 5;

  const int bid = blockIdx.x;
  const int wg = (bid & 7) * (NWG / 8) + (bid >> 3);   // bijective XCD swizzle
  const long m0 = (long)(wg / NX) * 256;
  const int n0 = (wg % NX) * 256;

  f32x16 acc[4][2];
#pragma unroll
  for (int a = 0; a < 4; ++a)
#pragma unroll
    for (int c = 0; c < 2; ++c) acc[a][c] = (f32x16)0.f;

  auto stage = [&](int t) {
    unsigned short* buf = sm + (t & 3) * 16384;
#pragma unroll
    for (int it = 0; it < 4; ++it) {
      int c = it * 512 + tid;
      if (it < 2) {                        // A: 1024 chunks (256 rows x 4 slots)
        int row = c >> 2, sl = c & 3;
        int slp = sl ^ ((row >> 1) & 3);
        gload16(Ap + (m0 + row) * (long)K + t * 32 + slp * 8, buf + c * 8);
      } else {                             // B: 1024 chunks
        int cb = c - 1024;
        int row = cb >> 2, sl = cb & 3;
        int slp = sl ^ ((row >> 1) & 3);
        gload16(Wt + (long)(n0 + row) * K + t * 32 + slp * 8, buf + 8192 + cb * 8);
      }
    }
  };

  auto compute = [&](const unsigned short* buf) {
#pragma unroll
    for (int ks = 0; ks < 2; ++ks) {
      bf16x8 bv[2];
#pragma unroll
      for (int fn = 0; fn < 2; ++fn) {
        int row = wc * 64 + fn * 32 + ln31;
        int s = (ks * 2 + kh) ^ ((row >> 1) & 3);
        bv[fn] = *(const bf16x8*)(buf + 8192 + row * 32 + s * 8);
      }
      bf16x8 av[4];
#pragma unroll
      for (int fm = 0; fm < 4; ++fm) {
        int row = wr * 128 + fm * 32 + ln31;
        int s = (ks * 2 + kh) ^ ((row >> 1) & 3);
        av[fm] = *(const bf16x8*)(buf + row * 32 + s * 8);
      }
      __builtin_amdgcn_s_setprio(1);
#pragma unroll
      for (int fm = 0; fm < 4; ++fm)
#pragma unroll
        for (int fn = 0; fn < 2; ++fn)
          acc[fm][fn] = __builtin_amdgcn_mfma_f32_32x32x16_bf16(
              av[fm], bv[fn], acc[fm][fn], 0, 0, 0);
      __builtin_amdgcn_s_setprio(0);
    }
  };

  stage(0);
  stage(1);
  stage(2);
#pragma unroll
  for (int t = 0; t < NT; ++t) {
    if (t <= NT - 3) vmwait<8>();          // t landed; t+1,t+2 stay in flight
    else if (t == NT - 2) vmwait<4>();
    else vmwait<0>();
    __builtin_amdgcn_s_barrier();
    asm volatile("" ::: "memory");
    if (t + 3 < NT) stage(t + 3);
    compute(sm + (t & 3) * 16384);
  }

  if constexpr (MODE == 0) {
    __hip_bfloat16* H = (__hip_bfloat16*)outp;
#pragma unroll
    for (int fm = 0; fm < 4; ++fm)
#pragma unroll
      for (int fn = 0; fn < 2; ++fn)
#pragma unroll
        for (int reg = 0; reg < 16; ++reg) {
          long row = m0 + wr * 128 + fm * 32 + (reg & 3) + 8 * (reg >> 2) + 4 * kh;
          int col = n0 + wc * 64 + fn * 32 + ln31;
          float v = acc[fm][fn][reg] * sc;
          float sg = frcp(1.f + __expf(-fabsf(v)));   // silu(|v|)/|v| = sigmoid(|v|)
          H[row * OSTRIDE + col] = __float2bfloat16(v * sg);
        }
  } else {
    float* O = (float*)outp;
#pragma unroll
    for (int fm = 0; fm < 4; ++fm)
#pragma unroll
      for (int fn = 0; fn < 2; ++fn)
#pragma unroll
        for (int reg = 0; reg < 16; ++reg) {
          long row = m0 + wr * 128 + fm * 32 + (reg & 3) + 8 * (reg >> 2) + 4 * kh;
          int col = n0 + wc * 64 + fn * 32 + ln31;
          O[row * OSTRIDE + col] = acc[fm][fn][reg] * sc;
        }
  }
}

// ---- l1/l2 GEMM core (r9-proven): 256 thr, 2x2 waves, dbuf, templated BK ---
template <int P, int BM, int BN, int K, int NN, int MODE, int BK>
__device__ __forceinline__ void gemm_core(
    unsigned short* sm, int b,
    const unsigned short* __restrict__ Ap, long planeA,
    const unsigned short* __restrict__ Wt,
    void* __restrict__ outp, long planeOut, int outOff, float sc) {
  constexpr int SLOTS = BK / 8;
  constexpr int SWM = SLOTS - 1;
  constexpr int KS = BK / 16;
  constexpr int RM = BM / 2, RN = BN / 2;
  constexpr int FM = RM / 32, FN = RN / 32;
  constexpr int CHA = P * BM * SLOTS, CHB = BN * SLOTS, TCH = CHA + CHB;
  constexpr int ITER = TCH / 256;
  static_assert(TCH % 256 == 0 && CHA % 256 == 0, "uniform staging");
  constexpr int ABUF = P * BM * BK;
  constexpr int BUFE = ABUF + BN * BK;
  constexpr int NT = K / BK;
  constexpr int NX = NN / BN;
  constexpr int NWG = (32768 / BM) * NX;
  static_assert(NWG % 8 == 0, "XCD swizzle");

  const int tid = threadIdx.x;
  const int lane = tid & 63, wv = tid >> 6;
  const int wr = wv >> 1, wc = wv & 1;
  const int ln31 = lane & 31, kh = lane >> 5;

  const int wg = (b & 7) * (NWG / 8) + (b >> 3);
  const long m0 = (long)(wg / NX) * BM;
  const int n0 = (wg % NX) * BN;

  f32x16 acc[P][FM][FN];
#pragma unroll
  for (int p = 0; p < P; ++p)
#pragma unroll
    for (int a = 0; a < FM; ++a)
#pragma unroll
      for (int c = 0; c < FN; ++c) acc[p][a][c] = (f32x16)0.f;

  auto stage = [&](unsigned short* buf, int t) {
#pragma unroll
    for (int it = 0; it < ITER; ++it) {
      int c = it * 256 + tid;
      if ((it + 1) * 256 <= CHA) {
        int p = c / (BM * SLOTS);
        int cp = c - p * (BM * SLOTS);
        int row = cp / SLOTS, sl = cp & SWM;
        int slp = sl ^ ((row >> 1) & SWM);
        gload16(Ap + (long)p * planeA + (m0 + row) * K + t * BK + slp * 8, buf + c * 8);
      } else {
        int cb = c - CHA;
        int row = cb / SLOTS, sl = cb & SWM;
        int slp = sl ^ ((row >> 1) & SWM);
        gload16(Wt + (long)(n0 + row) * K + t * BK + slp * 8, buf + ABUF + cb * 8);
      }
    }
  };

  auto compute = [&](const unsigned short* buf) {
#pragma unroll
    for (int ks = 0; ks < KS; ++ks) {
      bf16x8 bv[FN];
#pragma unroll
      for (int fn = 0; fn < FN; ++fn) {
        int row = wc * RN + fn * 32 + ln31;
        int s = (ks * 2 + kh) ^ ((row >> 1) & SWM);
        bv[fn] = *(const bf16x8*)(buf + ABUF + row * BK + s * 8);
      }
      bf16x8 av[P][FM];
#pragma unroll
      for (int p = 0; p < P; ++p)
#pragma unroll
        for (int fm = 0; fm < FM; ++fm) {
          int row = wr * RM + fm * 32 + ln31;
          int s = (ks * 2 + kh) ^ ((row >> 1) & SWM);
          av[p][fm] = *(const bf16x8*)(buf + p * BM * BK + row * BK + s * 8);
        }
      __builtin_amdgcn_s_setprio(1);
#pragma unroll
      for (int p = 0; p < P; ++p)
#pragma unroll
        for (int fm = 0; fm < FM; ++fm)
#pragma unroll
          for (int fn = 0; fn < FN; ++fn)
            acc[p][fm][fn] = __builtin_amdgcn_mfma_f32_32x32x16_bf16(
                av[p][fm], bv[fn], acc[p][fm][fn], 0, 0, 0);
      __builtin_amdgcn_s_setprio(0);
    }
  };

  stage(sm, 0);
  vmwait0();
  __builtin_amdgcn_s_barrier();
  asm volatile("" ::: "memory");
#pragma unroll
  for (int t = 0; t < NT; ++t) {
    if (t + 1 < NT) stage(sm + ((t + 1) & 1) * BUFE, t + 1);
    compute(sm + (t & 1) * BUFE);
    if (t + 1 < NT) {
      vmwait0();
      __builtin_amdgcn_s_barrier();
      asm volatile("" ::: "memory");
    }
  }

  if constexpr (MODE == 0) {
    __hip_bfloat16* H = (__hip_bfloat16*)outp;
#pragma unroll
    for (int fm = 0; fm < FM; ++fm)
#pragma unroll
      for (int fn = 0; fn < FN; ++fn)
#pragma unroll
        for (int reg = 0; reg < 16; ++reg) {
          long row = m0 + wr * RM + fm * 32 + (reg & 3) + 8 * (reg >> 2) + 4 * kh;
          int col = n0 + wc * RN + fn * 32 + ln31;
          float vs[P];
          float n2 = 0.f;
#pragma unroll
          for (int p = 0; p < P; ++p) {
            float v = acc[p][fm][fn][reg] * sc;
            vs[p] = v;
            n2 += v * v;
          }
          float nm = (P == 1) ? fabsf(vs[0]) : sqrtf(n2);
          float sg = frcp(1.f + __expf(-nm));
#pragma unroll
          for (int p = 0; p < P; ++p)
            H[p * planeOut + row * NN + col] = __float2bfloat16(vs[p] * sg);
        }
  } else {
    float* O = (float*)outp;
#pragma unroll
    for (int fm = 0; fm < FM; ++fm)
#pragma unroll
      for (int fn = 0; fn < FN; ++fn)
#pragma unroll
        for (int reg = 0; reg < 16; ++reg) {
          long row = m0 + wr * RM + fm * 32 + (reg & 3) + 8 * (reg >> 2) + 4 * kh;
          int col = n0 + wc * RN + fn * 32 + ln31;
          float* base = O + row * 1920 + outOff + (long)col * P;
          if constexpr (P == 1) {
            base[0] = acc[0][fm][fn][reg] * sc;
          } else if constexpr (P == 3) {
            f32x3 v3;
#pragma unroll
            for (int p = 0; p < 3; ++p) v3[p] = acc[p][fm][fn][reg] * sc;
            *(f32x3*)base = v3;
          } else {
            f32x4v v4;
#pragma unroll
            for (int p = 0; p < 4; ++p) v4[p] = acc[p][fm][fn][reg] * sc;
            *(f32x4v*)base = v4;
            base[4] = acc[4][fm][fn][reg] * sc;
          }
        }
  }
}

__global__ __launch_bounds__(256, 2) void g1b_kernel(
    const unsigned short* __restrict__ Xp, const unsigned short* __restrict__ W,
    unsigned short* __restrict__ Hp) {
  extern __shared__ unsigned short sm[];
  int b = blockIdx.x;
  if (b < 4096) {        // l1: P=3, 64x64, K=256, BK=64
    gemm_core<3, 64, 64, 256, 512, 0, 64>(sm, b, Xp + NL * 512, NL * 256, W + 524288,
                                          Hp + NL * 1024, NL * 512, 0, 0.0625f);
  } else {               // l2: P=5, 64x64, K=128, BK=32
    gemm_core<5, 64, 64, 128, 256, 0, 32>(sm, b - 4096, Xp + NL * 1280, NL * 128, W + 655360,
                                          Hp + NL * 2560, NL * 256, 0, 0.08838834765f);
  }
}

__global__ __launch_bounds__(256, 2) void g2b_kernel(
    const unsigned short* __restrict__ Hp, const unsigned short* __restrict__ W,
    float* __restrict__ out) {
  extern __shared__ unsigned short sm[];
  int b = blockIdx.x;
  if (b < 2048) {        // l1: P=3, 64x64, K=512, BK=64
    gemm_core<3, 64, 64, 512, 256, 1, 64>(sm, b, Hp + NL * 1024, NL * 512, W + 1212416,
                                          out, 0, 512, 0.04419417382f);
  } else {               // l2: P=5, 64x64, K=256, BK=32
    gemm_core<5, 64, 64, 256, 128, 1, 32>(sm, b - 2048, Hp + NL * 2560, NL * 256, W + 1343488,
                                          out, 0, 1280, 0.0625f);
  }
}

extern "C" void kernel_launch(void* const* d_in, const int* in_sizes, int n_in,
                              void* d_out, int out_size, void* d_ws, size_t ws_size,
                              hipStream_t stream) {
  const float* x = (const float*)d_in[0];
  const float* w1_0 = (const float*)d_in[1];
  const float* w1_1 = (const float*)d_in[2];
  const float* w1_2 = (const float*)d_in[3];
  const float* w2_0 = (const float*)d_in[4];
  const float* w2_1 = (const float*)d_in[5];
  const float* w2_2 = (const float*)d_in[6];
  float* out = (float*)d_out;

  unsigned short* Xp = (unsigned short*)d_ws;      // N*1920 bf16
  unsigned short* Hp = Xp + NL * 1920;             // N*3840 bf16
  unsigned short* W  = Hp + NL * 3840;             // 1376256 bf16 (all Wt blocks)

  {
    long total = NL * 896 + 1376256;
    prep_kernel<<<dim3((unsigned)((total + 255) / 256)), dim3(256), 0, stream>>>(
        x, w1_0, w1_1, w1_2, w2_0, w2_1, w2_2, Xp, W);
  }

  // l0 GEMMs: 256x256 tiles, 8 waves, depth-3 counted-vmcnt, 128KB LDS
  gemm0<512, 1024, 1024, 0><<<512, 512, 131072, stream>>>(Xp, W, Hp, 0.04419417382f);
  g1b_kernel<<<6144, 256, 65536, stream>>>(Xp, W, Hp);
  gemm0<1024, 512, 1920, 1><<<256, 512, 131072, stream>>>(Hp, W + 688128, out, 0.03125f);
  g2b_kernel<<<3072, 256, 65536, stream>>>(Hp, W, out);
}

// Round 13
// 395.384 us; speedup vs baseline: 1.0810x; 1.0514x over previous
//
#include <hip/hip_runtime.h>
#include <hip/hip_bf16.h>

#define NL 32768L

typedef __bf16 bf16x8 __attribute__((ext_vector_type(8)));
typedef float f32x4 __attribute__((ext_vector_type(4)));
typedef float f32x3 __attribute__((ext_vector_type(3)));
typedef float f32x4v __attribute__((ext_vector_type(4)));

__device__ __forceinline__ unsigned short f2bf(float f) {
  unsigned int u = __float_as_uint(f);
  u += 0x7FFFu + ((u >> 16) & 1u);   // round-to-nearest-even
  return (unsigned short)(u >> 16);
}

__device__ __forceinline__ float frcp(float x) {
  float r;
  asm("v_rcp_f32 %0, %1" : "=v"(r) : "v"(x));
  return r;
}

__device__ __forceinline__ void gload16(const void* g, void* l) {
  __builtin_amdgcn_global_load_lds((const __attribute__((address_space(1))) void*)g,
                                   (__attribute__((address_space(3))) void*)l, 16, 0, 0);
}

// ---- combined prep: x -> bf16 d-major planes, weights -> transposed bf16 ----
__global__ void prep_kernel(const float* __restrict__ x,
                            const float* __restrict__ w1_0, const float* __restrict__ w1_1,
                            const float* __restrict__ w1_2, const float* __restrict__ w2_0,
                            const float* __restrict__ w2_1, const float* __restrict__ w2_2,
                            unsigned short* __restrict__ Xp, unsigned short* __restrict__ W) {
  long i = (long)blockIdx.x * blockDim.x + threadIdx.x;
  if (i < NL * 512) {
    long n = i >> 9, u = i & 511;
    Xp[i] = f2bf(x[n * 1920 + u]);
  } else if (i < NL * 768) {
    long j = i - NL * 512;
    long n = j >> 8, u = j & 255;
    const float* s = x + n * 1920 + 512 + u * 3;
    unsigned short* d = Xp + NL * 512 + n * 256 + u;
    d[0]        = f2bf(s[0]);
    d[NL * 256] = f2bf(s[1]);
    d[NL * 512] = f2bf(s[2]);
  } else if (i < NL * 896) {
    long j = i - NL * 768;
    long n = j >> 7, u = j & 127;
    const float* s = x + n * 1920 + 1280 + u * 5;
    unsigned short* d = Xp + NL * 1280 + n * 128 + u;
#pragma unroll
    for (int k = 0; k < 5; ++k) d[k * NL * 128] = f2bf(s[k]);
  } else {
    long j = i - NL * 896;
    if (j < 524288) {            // w1_0: K=512, C=1024
      int c = (int)(j >> 9), r = (int)(j & 511);
      W[j] = f2bf(w1_0[(long)r * 1024 + c]);
    } else if (j < 655360) {     // w1_1: K=256, C=512
      long t = j - 524288; int c = (int)(t >> 8), r = (int)(t & 255);
      W[j] = f2bf(w1_1[(long)r * 512 + c]);
    } else if (j < 688128) {     // w1_2: K=128, C=256
      long t = j - 655360; int c = (int)(t >> 7), r = (int)(t & 127);
      W[j] = f2bf(w1_2[(long)r * 256 + c]);
    } else if (j < 1212416) {    // w2_0: K=1024, C=512
      long t = j - 688128; int c = (int)(t >> 10), r = (int)(t & 1023);
      W[j] = f2bf(w2_0[(long)r * 512 + c]);
    } else if (j < 1343488) {    // w2_1: K=512, C=256
      long t = j - 1212416; int c = (int)(t >> 9), r = (int)(t & 511);
      W[j] = f2bf(w2_1[(long)r * 256 + c]);
    } else if (j < 1376256) {    // w2_2: K=256, C=128
      long t = j - 1343488; int c = (int)(t >> 8), r = (int)(t & 255);
      W[j] = f2bf(w2_2[(long)r * 128 + c]);
    }
  }
}

// ---- m97-replica GEMM core: 256 thr, 4 waves 2x2, 16x16x32 MFMA, BK=32 -----
// SINGLE LDS buffer, two __syncthreads per K-step, NO prefetch. Relies on
// 3 blocks/CU TLP to hide the drain (m97/m114: 874-912 TF with this schedule).
// Bank swizzle: 16B slot ^= (row>>1)&3 on BOTH gload source and ds_read.
// MODE 0: normact across P planes -> bf16 planes.  MODE 1: f32 interleaved out.
template <int P, int BM, int BN, int K, int NN, int MODE>
__device__ __forceinline__ void gemm_core(
    unsigned short* sm, int b,
    const unsigned short* __restrict__ Ap, long planeA,
    const unsigned short* __restrict__ Wt,
    void* __restrict__ outp, long planeOut, int outOff, float sc) {
  constexpr int BK = 32;
  constexpr int RM = BM / 2, RN = BN / 2;        // per-wave tile
  constexpr int FM = RM / 16, FN = RN / 16;      // 16x16 frags
  constexpr int CHA = P * BM * 4, CHB = BN * 4, TCH = CHA + CHB;  // 16B chunks
  constexpr int ITER = TCH / 256;
  static_assert(TCH % 256 == 0 && CHA % 256 == 0, "uniform staging");
  constexpr int ABUF = P * BM * BK;              // elems
  constexpr int NT = K / BK;
  constexpr int NX = NN / BN;
  constexpr int NWG = (32768 / BM) * NX;
  static_assert(NWG % 8 == 0, "XCD swizzle");

  const int tid = threadIdx.x;
  const int lane = tid & 63, wv = tid >> 6;
  const int wr = wv >> 1, wc = wv & 1;
  const int fr = lane & 15, fq = lane >> 4;      // frag row/col, k-group

  const int wg = (b & 7) * (NWG / 8) + (b >> 3);   // bijective XCD swizzle
  const long m0 = (long)(wg / NX) * BM;
  const int n0 = (wg % NX) * BN;

  f32x4 acc[P][FM][FN];
#pragma unroll
  for (int p = 0; p < P; ++p)
#pragma unroll
    for (int a = 0; a < FM; ++a)
#pragma unroll
      for (int c = 0; c < FN; ++c) acc[p][a][c] = (f32x4){0.f, 0.f, 0.f, 0.f};

#pragma unroll 1
  for (int t = 0; t < NT; ++t) {
    // ---- stage K-step t into the single buffer ----
#pragma unroll
    for (int it = 0; it < ITER; ++it) {
      int c = it * 256 + tid;
      if ((it + 1) * 256 <= CHA) {       // compile-time A/B split per unrolled it
        int p = c / (BM * 4);
        int cp = c - p * (BM * 4);
        int row = cp >> 2, sl = cp & 3;
        int slp = sl ^ ((row >> 1) & 3);
        gload16(Ap + (long)p * planeA + (m0 + row) * K + t * BK + slp * 8, sm + c * 8);
      } else {
        int cb = c - CHA;
        int row = cb >> 2, sl = cb & 3;
        int slp = sl ^ ((row >> 1) & 3);
        gload16(Wt + (long)(n0 + row) * K + t * BK + slp * 8, sm + ABUF + cb * 8);
      }
    }
    __syncthreads();                     // drains vmcnt (loads landed) + barrier

    // ---- compute K-step t ----
    {
      bf16x8 bv[FN];
#pragma unroll
      for (int fn = 0; fn < FN; ++fn) {
        int row = wc * RN + fn * 16 + fr;
        int s = fq ^ ((row >> 1) & 3);
        bv[fn] = *(const bf16x8*)(sm + ABUF + row * BK + s * 8);
      }
#pragma unroll
      for (int p = 0; p < P; ++p)
#pragma unroll
        for (int fm = 0; fm < FM; ++fm) {
          int row = wr * RM + fm * 16 + fr;
          int s = fq ^ ((row >> 1) & 3);
          bf16x8 av = *(const bf16x8*)(sm + p * BM * BK + row * BK + s * 8);
#pragma unroll
          for (int fn = 0; fn < FN; ++fn)
            acc[p][fm][fn] = __builtin_amdgcn_mfma_f32_16x16x32_bf16(
                av, bv[fn], acc[p][fm][fn], 0, 0, 0);
        }
    }
    __syncthreads();                     // protect single buffer before next stage
  }

  if constexpr (MODE == 0) {
    __hip_bfloat16* H = (__hip_bfloat16*)outp;
#pragma unroll
    for (int fm = 0; fm < FM; ++fm)
#pragma unroll
      for (int fn = 0; fn < FN; ++fn)
#pragma unroll
        for (int r = 0; r < 4; ++r) {
          long row = m0 + wr * RM + fm * 16 + fq * 4 + r;
          int col = n0 + wc * RN + fn * 16 + fr;
          float vs[P];
          float n2 = 0.f;
#pragma unroll
          for (int p = 0; p < P; ++p) {
            float v = acc[p][fm][fn][r] * sc;
            vs[p] = v;
            n2 += v * v;
          }
          float nm = (P == 1) ? fabsf(vs[0]) : sqrtf(n2);
          float sg = frcp(1.f + __expf(-nm));   // silu(n)/n == sigmoid(n)
#pragma unroll
          for (int p = 0; p < P; ++p)
            H[p * planeOut + row * NN + col] = __float2bfloat16(vs[p] * sg);
        }
  } else {
    float* O = (float*)outp;
#pragma unroll
    for (int fm = 0; fm < FM; ++fm)
#pragma unroll
      for (int fn = 0; fn < FN; ++fn)
#pragma unroll
        for (int r = 0; r < 4; ++r) {
          long row = m0 + wr * RM + fm * 16 + fq * 4 + r;
          int col = n0 + wc * RN + fn * 16 + fr;
          float* base = O + row * 1920 + outOff + (long)col * P;
          if constexpr (P == 1) {
            base[0] = acc[0][fm][fn][r] * sc;
          } else if constexpr (P == 3) {
            f32x3 v3;
#pragma unroll
            for (int p = 0; p < 3; ++p) v3[p] = acc[p][fm][fn][r] * sc;
            *(f32x3*)base = v3;
          } else {
            f32x4v v4;
#pragma unroll
            for (int p = 0; p < 4; ++p) v4[p] = acc[p][fm][fn][r] * sc;
            *(f32x4v*)base = v4;
            base[4] = acc[4][fm][fn][r] * sc;
          }
        }
  }
}

// ---- fat dispatches: 256 thr, 24KB dynamic LDS, 3+ blocks/CU ---------------
__global__ __launch_bounds__(256, 3) void fat1_kernel(
    const unsigned short* __restrict__ Xp, const unsigned short* __restrict__ W,
    unsigned short* __restrict__ Hp) {
  extern __shared__ unsigned short sm[];
  int b = blockIdx.x;
  if (b < 2048) {        // l0: 128x128, K=512  (16KB buf)
    gemm_core<1, 128, 128, 512, 1024, 0>(sm, b, Xp, 0, W, Hp, 0, 0, 0.04419417382f);
  } else if (b < 4096) { // l1: P=3, 64x128, K=256  (20KB buf)
    gemm_core<3, 64, 128, 256, 512, 0>(sm, b - 2048, Xp + NL * 512, NL * 256, W + 524288,
                                       Hp + NL * 1024, NL * 512, 0, 0.0625f);
  } else {               // l2: P=5, 64x64, K=128  (24KB buf)
    gemm_core<5, 64, 64, 128, 256, 0>(sm, b - 4096, Xp + NL * 1280, NL * 128, W + 655360,
                                      Hp + NL * 2560, NL * 256, 0, 0.08838834765f);
  }
}

__global__ __launch_bounds__(256, 3) void fat2_kernel(
    const unsigned short* __restrict__ Hp, const unsigned short* __restrict__ W,
    float* __restrict__ out) {
  extern __shared__ unsigned short sm[];
  int b = blockIdx.x;
  if (b < 1024) {        // l0: 128x128, K=1024
    gemm_core<1, 128, 128, 1024, 512, 1>(sm, b, Hp, 0, W + 688128, out, 0, 0, 0.03125f);
  } else if (b < 2048) { // l1: P=3, 64x128, K=512
    gemm_core<3, 64, 128, 512, 256, 1>(sm, b - 1024, Hp + NL * 1024, NL * 512, W + 1212416,
                                       out, 0, 512, 0.04419417382f);
  } else {               // l2: P=5, 64x64, K=256
    gemm_core<5, 64, 64, 256, 128, 1>(sm, b - 2048, Hp + NL * 2560, NL * 256, W + 1343488,
                                      out, 0, 1280, 0.0625f);
  }
}

extern "C" void kernel_launch(void* const* d_in, const int* in_sizes, int n_in,
                              void* d_out, int out_size, void* d_ws, size_t ws_size,
                              hipStream_t stream) {
  const float* x = (const float*)d_in[0];
  const float* w1_0 = (const float*)d_in[1];
  const float* w1_1 = (const float*)d_in[2];
  const float* w1_2 = (const float*)d_in[3];
  const float* w2_0 = (const float*)d_in[4];
  const float* w2_1 = (const float*)d_in[5];
  const float* w2_2 = (const float*)d_in[6];
  float* out = (float*)d_out;

  unsigned short* Xp = (unsigned short*)d_ws;      // N*1920 bf16
  unsigned short* Hp = Xp + NL * 1920;             // N*3840 bf16
  unsigned short* W  = Hp + NL * 3840;             // 1376256 bf16 (all Wt blocks)

  {
    long total = NL * 896 + 1376256;
    prep_kernel<<<dim3((unsigned)((total + 255) / 256)), dim3(256), 0, stream>>>(
        x, w1_0, w1_1, w1_2, w2_0, w2_1, w2_2, Xp, W);
  }

  fat1_kernel<<<6144, 256, 24576, stream>>>(Xp, W, Hp);
  fat2_kernel<<<3072, 256, 24576, stream>>>(Hp, W, out);
}

// Round 14
// 392.711 us; speedup vs baseline: 1.0883x; 1.0068x over previous
//
#include <hip/hip_runtime.h>
#include <hip/hip_bf16.h>

#define NL 32768L

typedef __bf16 bf16x8 __attribute__((ext_vector_type(8)));
typedef float f32x16 __attribute__((ext_vector_type(16)));
typedef float f32x4 __attribute__((ext_vector_type(4)));
typedef float f32x3 __attribute__((ext_vector_type(3)));
typedef float f32x4v __attribute__((ext_vector_type(4)));

__device__ __forceinline__ unsigned short f2bf(float f) {
  unsigned int u = __float_as_uint(f);
  u += 0x7FFFu + ((u >> 16) & 1u);   // round-to-nearest-even
  return (unsigned short)(u >> 16);
}

__device__ __forceinline__ float frcp(float x) {
  float r;
  asm("v_rcp_f32 %0, %1" : "=v"(r) : "v"(x));
  return r;
}

__device__ __forceinline__ void gload16(const void* g, void* l) {
  __builtin_amdgcn_global_load_lds((const __attribute__((address_space(1))) void*)g,
                                   (__attribute__((address_space(3))) void*)l, 16, 0, 0);
}

template <int N>
__device__ __forceinline__ void vmwait() {
  if constexpr (N == 0) asm volatile("s_waitcnt vmcnt(0)" ::: "memory");
  else if constexpr (N == 4) asm volatile("s_waitcnt vmcnt(4)" ::: "memory");
  else if constexpr (N == 8) asm volatile("s_waitcnt vmcnt(8)" ::: "memory");
  else if constexpr (N == 12) asm volatile("s_waitcnt vmcnt(12)" ::: "memory");
  else static_assert(N == 0, "unsupported vmcnt");
}

// ---- combined prep: x -> bf16 d-major planes, weights -> transposed bf16 ----
__global__ void prep_kernel(const float* __restrict__ x,
                            const float* __restrict__ w1_0, const float* __restrict__ w1_1,
                            const float* __restrict__ w1_2, const float* __restrict__ w2_0,
                            const float* __restrict__ w2_1, const float* __restrict__ w2_2,
                            unsigned short* __restrict__ Xp, unsigned short* __restrict__ W) {
  long i = (long)blockIdx.x * blockDim.x + threadIdx.x;
  if (i < NL * 512) {
    long n = i >> 9, u = i & 511;
    Xp[i] = f2bf(x[n * 1920 + u]);
  } else if (i < NL * 768) {
    long j = i - NL * 512;
    long n = j >> 8, u = j & 255;
    const float* s = x + n * 1920 + 512 + u * 3;
    unsigned short* d = Xp + NL * 512 + n * 256 + u;
    d[0]        = f2bf(s[0]);
    d[NL * 256] = f2bf(s[1]);
    d[NL * 512] = f2bf(s[2]);
  } else if (i < NL * 896) {
    long j = i - NL * 768;
    long n = j >> 7, u = j & 127;
    const float* s = x + n * 1920 + 1280 + u * 5;
    unsigned short* d = Xp + NL * 1280 + n * 128 + u;
#pragma unroll
    for (int k = 0; k < 5; ++k) d[k * NL * 128] = f2bf(s[k]);
  } else {
    long j = i - NL * 896;
    if (j < 524288) {            // w1_0: K=512, C=1024
      int c = (int)(j >> 9), r = (int)(j & 511);
      W[j] = f2bf(w1_0[(long)r * 1024 + c]);
    } else if (j < 655360) {     // w1_1: K=256, C=512
      long t = j - 524288; int c = (int)(t >> 8), r = (int)(t & 255);
      W[j] = f2bf(w1_1[(long)r * 512 + c]);
    } else if (j < 688128) {     // w1_2: K=128, C=256
      long t = j - 655360; int c = (int)(t >> 7), r = (int)(t & 127);
      W[j] = f2bf(w1_2[(long)r * 256 + c]);
    } else if (j < 1212416) {    // w2_0: K=1024, C=512
      long t = j - 688128; int c = (int)(t >> 10), r = (int)(t & 1023);
      W[j] = f2bf(w2_0[(long)r * 512 + c]);
    } else if (j < 1343488) {    // w2_1: K=512, C=256
      long t = j - 1212416; int c = (int)(t >> 9), r = (int)(t & 511);
      W[j] = f2bf(w2_1[(long)r * 256 + c]);
    } else if (j < 1376256) {    // w2_2: K=256, C=128
      long t = j - 1343488; int c = (int)(t >> 8), r = (int)(t & 255);
      W[j] = f2bf(w2_2[(long)r * 128 + c]);
    }
  }
}

// ---- gemm0: l0 GEMM, 512 thr, 8 waves 2x4, per-wave 128x64, DEPTH-4 --------
// BM=BN=256, BK=32 substeps, 5 LDS buffers (32KB each = 160KB), counted vmcnt:
// steady {vmwait(12); barrier; stage(t+4); compute(t)} -- 3 substeps (~770cyc+)
// always in flight, matching HBM-class latency. Race-free: stage(t+4) writes
// buf[(t-1)%5], whose last reads were in substep t-1, barrier t between.
// Wait ladder: outstanding after check = 4*|{t+1..min(t+3,NT-1)}| -> 12/8/4/0.
// NCOL: output columns. OSTRIDE: output row stride.
// MODE 0: normact -> bf16 H[row*OSTRIDE+col].  MODE 1: f32 O[row*OSTRIDE+col].
template <int K, int NCOL, int OSTRIDE, int MODE>
__global__ __launch_bounds__(512, 2) void gemm0(
    const unsigned short* __restrict__ Ap, const unsigned short* __restrict__ Wt,
    void* __restrict__ outp, float sc) {
  constexpr int NT = K / 32;
  constexpr int NX = NCOL / 256;
  constexpr int NWG = 128 * NX;
  static_assert(NCOL % 256 == 0 && NWG % 8 == 0 && NT >= 5, "decomposition");
  extern __shared__ unsigned short sm[];

  const int tid = threadIdx.x;
  const int lane = tid & 63, wv = tid >> 6;
  const int wr = wv >> 2, wc = wv & 3;        // 2x4 wave grid
  const int ln31 = lane & 31, kh = lane >> 5;

  const int bid = blockIdx.x;
  const int wg = (bid & 7) * (NWG / 8) + (bid >> 3);   // bijective XCD swizzle
  const long m0 = (long)(wg / NX) * 256;
  const int n0 = (wg % NX) * 256;

  f32x16 acc[4][2];
#pragma unroll
  for (int a = 0; a < 4; ++a)
#pragma unroll
    for (int c = 0; c < 2; ++c) acc[a][c] = (f32x16)0.f;

  auto stage = [&](int t) {
    unsigned short* buf = sm + (t % 5) * 16384;
#pragma unroll
    for (int it = 0; it < 4; ++it) {
      int c = it * 512 + tid;
      if (it < 2) {                        // A: 1024 chunks (256 rows x 4 slots)
        int row = c >> 2, sl = c & 3;
        int slp = sl ^ ((row >> 1) & 3);
        gload16(Ap + (m0 + row) * (long)K + t * 32 + slp * 8, buf + c * 8);
      } else {                             // B: 1024 chunks
        int cb = c - 1024;
        int row = cb >> 2, sl = cb & 3;
        int slp = sl ^ ((row >> 1) & 3);
        gload16(Wt + (long)(n0 + row) * K + t * 32 + slp * 8, buf + 8192 + cb * 8);
      }
    }
  };

  auto compute = [&](const unsigned short* buf) {
#pragma unroll
    for (int ks = 0; ks < 2; ++ks) {
      bf16x8 bv[2];
#pragma unroll
      for (int fn = 0; fn < 2; ++fn) {
        int row = wc * 64 + fn * 32 + ln31;
        int s = (ks * 2 + kh) ^ ((row >> 1) & 3);
        bv[fn] = *(const bf16x8*)(buf + 8192 + row * 32 + s * 8);
      }
      bf16x8 av[4];
#pragma unroll
      for (int fm = 0; fm < 4; ++fm) {
        int row = wr * 128 + fm * 32 + ln31;
        int s = (ks * 2 + kh) ^ ((row >> 1) & 3);
        av[fm] = *(const bf16x8*)(buf + row * 32 + s * 8);
      }
      __builtin_amdgcn_s_setprio(1);
#pragma unroll
      for (int fm = 0; fm < 4; ++fm)
#pragma unroll
        for (int fn = 0; fn < 2; ++fn)
          acc[fm][fn] = __builtin_amdgcn_mfma_f32_32x32x16_bf16(
              av[fm], bv[fn], acc[fm][fn], 0, 0, 0);
      __builtin_amdgcn_s_setprio(0);
    }
  };

  stage(0);
  stage(1);
  stage(2);
  stage(3);
#pragma unroll
  for (int t = 0; t < NT; ++t) {
    if (t <= NT - 4) vmwait<12>();       // t landed; t+1..t+3 stay in flight
    else if (t == NT - 3) vmwait<8>();
    else if (t == NT - 2) vmwait<4>();
    else vmwait<0>();
    __builtin_amdgcn_s_barrier();
    asm volatile("" ::: "memory");
    if (t + 4 < NT) stage(t + 4);
    compute(sm + (t % 5) * 16384);
  }

  if constexpr (MODE == 0) {
    __hip_bfloat16* H = (__hip_bfloat16*)outp;
#pragma unroll
    for (int fm = 0; fm < 4; ++fm)
#pragma unroll
      for (int fn = 0; fn < 2; ++fn)
#pragma unroll
        for (int reg = 0; reg < 16; ++reg) {
          long row = m0 + wr * 128 + fm * 32 + (reg & 3) + 8 * (reg >> 2) + 4 * kh;
          int col = n0 + wc * 64 + fn * 32 + ln31;
          float v = acc[fm][fn][reg] * sc;
          float sg = frcp(1.f + __expf(-fabsf(v)));   // silu(|v|)/|v| = sigmoid(|v|)
          H[row * OSTRIDE + col] = __float2bfloat16(v * sg);
        }
  } else {
    float* O = (float*)outp;
#pragma unroll
    for (int fm = 0; fm < 4; ++fm)
#pragma unroll
      for (int fn = 0; fn < 2; ++fn)
#pragma unroll
        for (int reg = 0; reg < 16; ++reg) {
          long row = m0 + wr * 128 + fm * 32 + (reg & 3) + 8 * (reg >> 2) + 4 * kh;
          int col = n0 + wc * 64 + fn * 32 + ln31;
          O[row * OSTRIDE + col] = acc[fm][fn][reg] * sc;
        }
  }
}

// ---- l1/l2 core (r13): 256 thr, 2x2 waves, 16x16x32, single buffer ---------
template <int P, int BM, int BN, int K, int NN, int MODE>
__device__ __forceinline__ void gemm_core(
    unsigned short* sm, int b,
    const unsigned short* __restrict__ Ap, long planeA,
    const unsigned short* __restrict__ Wt,
    void* __restrict__ outp, long planeOut, int outOff, float sc) {
  constexpr int BK = 32;
  constexpr int RM = BM / 2, RN = BN / 2;
  constexpr int FM = RM / 16, FN = RN / 16;
  constexpr int CHA = P * BM * 4, CHB = BN * 4, TCH = CHA + CHB;
  constexpr int ITER = TCH / 256;
  static_assert(TCH % 256 == 0 && CHA % 256 == 0, "uniform staging");
  constexpr int ABUF = P * BM * BK;
  constexpr int NT = K / BK;
  constexpr int NX = NN / BN;
  constexpr int NWG = (32768 / BM) * NX;
  static_assert(NWG % 8 == 0, "XCD swizzle");

  const int tid = threadIdx.x;
  const int lane = tid & 63, wv = tid >> 6;
  const int wr = wv >> 1, wc = wv & 1;
  const int fr = lane & 15, fq = lane >> 4;

  const int wg = (b & 7) * (NWG / 8) + (b >> 3);
  const long m0 = (long)(wg / NX) * BM;
  const int n0 = (wg % NX) * BN;

  f32x4 acc[P][FM][FN];
#pragma unroll
  for (int p = 0; p < P; ++p)
#pragma unroll
    for (int a = 0; a < FM; ++a)
#pragma unroll
      for (int c = 0; c < FN; ++c) acc[p][a][c] = (f32x4){0.f, 0.f, 0.f, 0.f};

#pragma unroll 1
  for (int t = 0; t < NT; ++t) {
#pragma unroll
    for (int it = 0; it < ITER; ++it) {
      int c = it * 256 + tid;
      if ((it + 1) * 256 <= CHA) {
        int p = c / (BM * 4);
        int cp = c - p * (BM * 4);
        int row = cp >> 2, sl = cp & 3;
        int slp = sl ^ ((row >> 1) & 3);
        gload16(Ap + (long)p * planeA + (m0 + row) * K + t * BK + slp * 8, sm + c * 8);
      } else {
        int cb = c - CHA;
        int row = cb >> 2, sl = cb & 3;
        int slp = sl ^ ((row >> 1) & 3);
        gload16(Wt + (long)(n0 + row) * K + t * BK + slp * 8, sm + ABUF + cb * 8);
      }
    }
    __syncthreads();
    {
      bf16x8 bv[FN];
#pragma unroll
      for (int fn = 0; fn < FN; ++fn) {
        int row = wc * RN + fn * 16 + fr;
        int s = fq ^ ((row >> 1) & 3);
        bv[fn] = *(const bf16x8*)(sm + ABUF + row * BK + s * 8);
      }
#pragma unroll
      for (int p = 0; p < P; ++p)
#pragma unroll
        for (int fm = 0; fm < FM; ++fm) {
          int row = wr * RM + fm * 16 + fr;
          int s = fq ^ ((row >> 1) & 3);
          bf16x8 av = *(const bf16x8*)(sm + p * BM * BK + row * BK + s * 8);
#pragma unroll
          for (int fn = 0; fn < FN; ++fn)
            acc[p][fm][fn] = __builtin_amdgcn_mfma_f32_16x16x32_bf16(
                av, bv[fn], acc[p][fm][fn], 0, 0, 0);
        }
    }
    __syncthreads();
  }

  if constexpr (MODE == 0) {
    __hip_bfloat16* H = (__hip_bfloat16*)outp;
#pragma unroll
    for (int fm = 0; fm < FM; ++fm)
#pragma unroll
      for (int fn = 0; fn < FN; ++fn)
#pragma unroll
        for (int r = 0; r < 4; ++r) {
          long row = m0 + wr * RM + fm * 16 + fq * 4 + r;
          int col = n0 + wc * RN + fn * 16 + fr;
          float vs[P];
          float n2 = 0.f;
#pragma unroll
          for (int p = 0; p < P; ++p) {
            float v = acc[p][fm][fn][r] * sc;
            vs[p] = v;
            n2 += v * v;
          }
          float nm = sqrtf(n2);
          float sg = frcp(1.f + __expf(-nm));   // silu(n)/n == sigmoid(n)
#pragma unroll
          for (int p = 0; p < P; ++p)
            H[p * planeOut + row * NN + col] = __float2bfloat16(vs[p] * sg);
        }
  } else {
    float* O = (float*)outp;
#pragma unroll
    for (int fm = 0; fm < FM; ++fm)
#pragma unroll
      for (int fn = 0; fn < FN; ++fn)
#pragma unroll
        for (int r = 0; r < 4; ++r) {
          long row = m0 + wr * RM + fm * 16 + fq * 4 + r;
          int col = n0 + wc * RN + fn * 16 + fr;
          float* base = O + row * 1920 + outOff + (long)col * P;
          if constexpr (P == 3) {
            f32x3 v3;
#pragma unroll
            for (int p = 0; p < 3; ++p) v3[p] = acc[p][fm][fn][r] * sc;
            *(f32x3*)base = v3;
          } else {
            f32x4v v4;
#pragma unroll
            for (int p = 0; p < 4; ++p) v4[p] = acc[p][fm][fn][r] * sc;
            *(f32x4v*)base = v4;
            base[4] = acc[4][fm][fn][r] * sc;
          }
        }
  }
}

// ---- l1/l2 fat dispatches (24KB dynamic LDS) -------------------------------
__global__ __launch_bounds__(256, 3) void g1b_kernel(
    const unsigned short* __restrict__ Xp, const unsigned short* __restrict__ W,
    unsigned short* __restrict__ Hp) {
  extern __shared__ unsigned short sm[];
  int b = blockIdx.x;
  if (b < 2048) {        // l1: P=3, 64x128, K=256
    gemm_core<3, 64, 128, 256, 512, 0>(sm, b, Xp + NL * 512, NL * 256, W + 524288,
                                       Hp + NL * 1024, NL * 512, 0, 0.0625f);
  } else {               // l2: P=5, 64x64, K=128
    gemm_core<5, 64, 64, 128, 256, 0>(sm, b - 2048, Xp + NL * 1280, NL * 128, W + 655360,
                                      Hp + NL * 2560, NL * 256, 0, 0.08838834765f);
  }
}

__global__ __launch_bounds__(256, 3) void g2b_kernel(
    const unsigned short* __restrict__ Hp, const unsigned short* __restrict__ W,
    float* __restrict__ out) {
  extern __shared__ unsigned short sm[];
  int b = blockIdx.x;
  if (b < 1024) {        // l1: P=3, 64x128, K=512
    gemm_core<3, 64, 128, 512, 256, 1>(sm, b, Hp + NL * 1024, NL * 512, W + 1212416,
                                       out, 0, 512, 0.04419417382f);
  } else {               // l2: P=5, 64x64, K=256
    gemm_core<5, 64, 64, 256, 128, 1>(sm, b - 1024, Hp + NL * 2560, NL * 256, W + 1343488,
                                      out, 0, 1280, 0.0625f);
  }
}

extern "C" void kernel_launch(void* const* d_in, const int* in_sizes, int n_in,
                              void* d_out, int out_size, void* d_ws, size_t ws_size,
                              hipStream_t stream) {
  const float* x = (const float*)d_in[0];
  const float* w1_0 = (const float*)d_in[1];
  const float* w1_1 = (const float*)d_in[2];
  const float* w1_2 = (const float*)d_in[3];
  const float* w2_0 = (const float*)d_in[4];
  const float* w2_1 = (const float*)d_in[5];
  const float* w2_2 = (const float*)d_in[6];
  float* out = (float*)d_out;

  unsigned short* Xp = (unsigned short*)d_ws;      // N*1920 bf16
  unsigned short* Hp = Xp + NL * 1920;             // N*3840 bf16
  unsigned short* W  = Hp + NL * 3840;             // 1376256 bf16 (all Wt blocks)

  {
    long total = NL * 896 + 1376256;
    prep_kernel<<<dim3((unsigned)((total + 255) / 256)), dim3(256), 0, stream>>>(
        x, w1_0, w1_1, w1_2, w2_0, w2_1, w2_2, Xp, W);
  }

  // l0-L1: depth-4 counted-vmcnt, 160KB LDS (5 x 32KB buffers)
  gemm0<512, 1024, 1024, 0><<<512, 512, 163840, stream>>>(Xp, W, Hp, 0.04419417382f);
  g1b_kernel<<<4096, 256, 24576, stream>>>(Xp, W, Hp);
  // l0-L2: reads Hp[:, :1024] (from gemm0-L1 only)
  gemm0<1024, 512, 1920, 1><<<256, 512, 163840, stream>>>(Hp, W + 688128, out, 0.03125f);
  g2b_kernel<<<2048, 256, 24576, stream>>>(Hp, W, out);
}

// Round 15
// 381.207 us; speedup vs baseline: 1.1212x; 1.0302x over previous
//
#include <hip/hip_runtime.h>
#include <hip/hip_bf16.h>

#define NL 32768L

typedef __bf16 bf16x8 __attribute__((ext_vector_type(8)));
typedef float f32x16 __attribute__((ext_vector_type(16)));
typedef float f32x3 __attribute__((ext_vector_type(3)));
typedef float f32x4v __attribute__((ext_vector_type(4)));

__device__ __forceinline__ unsigned short f2bf(float f) {
  unsigned int u = __float_as_uint(f);
  u += 0x7FFFu + ((u >> 16) & 1u);   // round-to-nearest-even
  return (unsigned short)(u >> 16);
}

__device__ __forceinline__ float frcp(float x) {
  float r;
  asm("v_rcp_f32 %0, %1" : "=v"(r) : "v"(x));
  return r;
}

__device__ __forceinline__ void gload16(const void* g, void* l) {
  __builtin_amdgcn_global_load_lds((const __attribute__((address_space(1))) void*)g,
                                   (__attribute__((address_space(3))) void*)l, 16, 0, 0);
}

template <int N>
__device__ __forceinline__ void vmwait() {
  if constexpr (N == 0) asm volatile("s_waitcnt vmcnt(0)" ::: "memory");
  else if constexpr (N == 4) asm volatile("s_waitcnt vmcnt(4)" ::: "memory");
  else static_assert(N == 0, "unsupported vmcnt");
}

// ---- combined prep: x -> bf16 d-major planes, weights -> transposed bf16 ----
__global__ void prep_kernel(const float* __restrict__ x,
                            const float* __restrict__ w1_0, const float* __restrict__ w1_1,
                            const float* __restrict__ w1_2, const float* __restrict__ w2_0,
                            const float* __restrict__ w2_1, const float* __restrict__ w2_2,
                            unsigned short* __restrict__ Xp, unsigned short* __restrict__ W) {
  long i = (long)blockIdx.x * blockDim.x + threadIdx.x;
  if (i < NL * 512) {
    long n = i >> 9, u = i & 511;
    Xp[i] = f2bf(x[n * 1920 + u]);
  } else if (i < NL * 768) {
    long j = i - NL * 512;
    long n = j >> 8, u = j & 255;
    const float* s = x + n * 1920 + 512 + u * 3;
    unsigned short* d = Xp + NL * 512 + n * 256 + u;
    d[0]        = f2bf(s[0]);
    d[NL * 256] = f2bf(s[1]);
    d[NL * 512] = f2bf(s[2]);
  } else if (i < NL * 896) {
    long j = i - NL * 768;
    long n = j >> 7, u = j & 127;
    const float* s = x + n * 1920 + 1280 + u * 5;
    unsigned short* d = Xp + NL * 1280 + n * 128 + u;
#pragma unroll
    for (int k = 0; k < 5; ++k) d[k * NL * 128] = f2bf(s[k]);
  } else {
    long j = i - NL * 896;
    if (j < 524288) {            // w1_0: K=512, C=1024
      int c = (int)(j >> 9), r = (int)(j & 511);
      W[j] = f2bf(w1_0[(long)r * 1024 + c]);
    } else if (j < 655360) {     // w1_1: K=256, C=512
      long t = j - 524288; int c = (int)(t >> 8), r = (int)(t & 255);
      W[j] = f2bf(w1_1[(long)r * 512 + c]);
    } else if (j < 688128) {     // w1_2: K=128, C=256
      long t = j - 655360; int c = (int)(t >> 7), r = (int)(t & 127);
      W[j] = f2bf(w1_2[(long)r * 256 + c]);
    } else if (j < 1212416) {    // w2_0: K=1024, C=512
      long t = j - 688128; int c = (int)(t >> 10), r = (int)(t & 1023);
      W[j] = f2bf(w2_0[(long)r * 512 + c]);
    } else if (j < 1343488) {    // w2_1: K=512, C=256
      long t = j - 1212416; int c = (int)(t >> 9), r = (int)(t & 511);
      W[j] = f2bf(w2_1[(long)r * 256 + c]);
    } else if (j < 1376256) {    // w2_2: K=256, C=128
      long t = j - 1343488; int c = (int)(t >> 8), r = (int)(t & 255);
      W[j] = f2bf(w2_2[(long)r * 128 + c]);
    }
  }
}

// ---- GEMM core: 512 thr, counted-vmcnt 3-sub-buffer pipeline, BK2=32 -------
// Schedule (r4-proven): {vmcnt(ISSUES); barrier; stage(t+2 -> buf[(t+2)%3]);
// compute(buf[t%3])}. Loads for t+1/t+2 stay in flight across the barrier.
// Bank swizzle: 16B slot ^= (row>>1)&3 on BOTH gload source and ds_read.
// MODE 0: normact across P planes -> bf16 planes.  MODE 1: f32 interleaved out.
template <int P, int BM, int BN, int K, int NN, int MODE, int WM, int WN>
__device__ __forceinline__ void gemm_core(
    unsigned short* sm, int b,
    const unsigned short* __restrict__ Ap, long planeA,
    const unsigned short* __restrict__ Wt,
    void* __restrict__ outp, long planeOut, int outOff, float sc) {
  constexpr int BK = 32;
  constexpr int RM = BM / WM, RN = BN / WN;     // per-wave tile
  constexpr int FM = RM / 32, FN = RN / 32;
  constexpr int CHA = P * BM * 4;               // A 16B-chunks per substep
  constexpr int TCH = CHA + BN * 4;
  constexpr int ITER = (TCH + 511) / 512;       // loads per thread (uniform)
  constexpr int BUFE = TCH * 8;                 // elems per sub-buffer
  constexpr int NT = K / BK;
  constexpr int NX = NN / BN;
  constexpr int NWG = (32768 / BM) * NX;

  const int tid = threadIdx.x;
  const int lane = tid & 63, wv = tid >> 6;
  const int wr = wv / WN, wc = wv % WN;
  const int ln31 = lane & 31, kh = lane >> 5;

  const int wg = (b & 7) * (NWG / 8) + (b >> 3);   // bijective XCD swizzle
  const long m0 = (long)(wg / NX) * BM;
  const int n0 = (wg % NX) * BN;

  f32x16 acc[P][FM][FN];
#pragma unroll
  for (int p = 0; p < P; ++p)
#pragma unroll
    for (int a = 0; a < FM; ++a)
#pragma unroll
      for (int c = 0; c < FN; ++c) acc[p][a][c] = (f32x16)0.f;

  auto stage = [&](unsigned short* buf, int t) {
#pragma unroll
    for (int it = 0; it < ITER; ++it) {
      int c = it * 512 + tid;
      if constexpr (ITER * 512 != TCH) {
        if (c >= TCH) c -= 512;          // duplicate a B-chunk (benign), keeps
      }                                  // per-thread vmcnt issue count uniform
      const unsigned short* src;
      if (c < CHA) {
        int p = c / (BM * 4);
        int cp = c - p * (BM * 4);
        int row = cp >> 2, sl = cp & 3;
        int slp = sl ^ ((row >> 1) & 3);
        src = Ap + (long)p * planeA + (m0 + row) * K + t * BK + slp * 8;
      } else {
        int cb = c - CHA;
        int row = cb >> 2, sl = cb & 3;
        int slp = sl ^ ((row >> 1) & 3);
        src = Wt + (long)(n0 + row) * K + t * BK + slp * 8;
      }
      gload16(src, buf + c * 8);         // single convergent issue per it
    }
  };

  auto compute = [&](const unsigned short* buf) {
#pragma unroll
    for (int ks = 0; ks < 2; ++ks) {
      bf16x8 bv[FN];
#pragma unroll
      for (int fn = 0; fn < FN; ++fn) {
        int row = wc * RN + fn * 32 + ln31;
        int s = (ks * 2 + kh) ^ ((row >> 1) & 3);
        bv[fn] = *(const bf16x8*)(buf + CHA * 8 + row * BK + s * 8);
      }
      bf16x8 av[P][FM];
#pragma unroll
      for (int p = 0; p < P; ++p)
#pragma unroll
        for (int fm = 0; fm < FM; ++fm) {
          int row = wr * RM + fm * 32 + ln31;
          int s = (ks * 2 + kh) ^ ((row >> 1) & 3);
          av[p][fm] = *(const bf16x8*)(buf + p * BM * BK + row * BK + s * 8);
        }
      __builtin_amdgcn_s_setprio(1);
#pragma unroll
      for (int p = 0; p < P; ++p)
#pragma unroll
        for (int fm = 0; fm < FM; ++fm)
#pragma unroll
          for (int fn = 0; fn < FN; ++fn)
            acc[p][fm][fn] = __builtin_amdgcn_mfma_f32_32x32x16_bf16(
                av[p][fm], bv[fn], acc[p][fm][fn], 0, 0, 0);
      __builtin_amdgcn_s_setprio(0);
    }
  };

  stage(sm, 0);
  stage(sm + BUFE, 1);
#pragma unroll
  for (int t = 0; t < NT; ++t) {
    if (t < NT - 1) vmwait<ITER>();      // step-t landed; t+1 stays in flight
    else vmwait<0>();
    __builtin_amdgcn_s_barrier();
    asm volatile("" ::: "memory");
    if (t + 2 < NT) stage(sm + ((t + 2) % 3) * BUFE, t + 2);
    compute(sm + (t % 3) * BUFE);
  }

  if constexpr (MODE == 0) {
    __hip_bfloat16* H = (__hip_bfloat16*)outp;
#pragma unroll
    for (int fm = 0; fm < FM; ++fm)
#pragma unroll
      for (int fn = 0; fn < FN; ++fn)
#pragma unroll
        for (int reg = 0; reg < 16; ++reg) {
          long row = m0 + wr * RM + fm * 32 + (reg & 3) + 8 * (reg >> 2) + 4 * kh;
          int col = n0 + wc * RN + fn * 32 + ln31;
          float vs[P];
          float n2 = 0.f;
#pragma unroll
          for (int p = 0; p < P; ++p) {
            float v = acc[p][fm][fn][reg] * sc;
            vs[p] = v;
            n2 += v * v;
          }
          float nm = (P == 1) ? fabsf(vs[0]) : sqrtf(n2);
          float sg = frcp(1.f + __expf(-nm));   // silu(n)/n == sigmoid(n)
#pragma unroll
          for (int p = 0; p < P; ++p)
            H[p * planeOut + row * NN + col] = __float2bfloat16(vs[p] * sg);
        }
  } else {
    float* O = (float*)outp;
#pragma unroll
    for (int fm = 0; fm < FM; ++fm)
#pragma unroll
      for (int fn = 0; fn < FN; ++fn)
#pragma unroll
        for (int reg = 0; reg < 16; ++reg) {
          long row = m0 + wr * RM + fm * 32 + (reg & 3) + 8 * (reg >> 2) + 4 * kh;
          int col = n0 + wc * RN + fn * 32 + ln31;
          float* base = O + row * 1920 + outOff + (long)col * P;
          if constexpr (P == 1) {
            base[0] = acc[0][fm][fn][reg] * sc;
          } else if constexpr (P == 3) {
            f32x3 v3;
#pragma unroll
            for (int p = 0; p < 3; ++p) v3[p] = acc[p][fm][fn][reg] * sc;
            *(f32x3*)base = v3;
          } else {
            f32x4v v4;
#pragma unroll
            for (int p = 0; p < 4; ++p) v4[p] = acc[p][fm][fn][reg] * sc;
            *(f32x4v*)base = v4;
            base[4] = acc[4][fm][fn][reg] * sc;
          }
        }
  }
}

// ---- fat dispatches (512 threads; longest sub-GEMM first) ------------------
__global__ __launch_bounds__(512, 2) void fat1_kernel(
    const unsigned short* __restrict__ Xp, const unsigned short* __restrict__ W,
    unsigned short* __restrict__ Hp) {
  extern __shared__ unsigned short sm[];
  int b = blockIdx.x;
  if (b < 512) {         // l0: 256x256, K=512, waves 2x4 (128x64/wave)
    gemm_core<1, 256, 256, 512, 1024, 0, 2, 4>(sm, b, Xp, 0, W, Hp, 0, 0, 0.04419417382f);
  } else if (b < 1536) { // l1: P=3, 128x128, K=256, waves 2x4 (64x32/wave)
    gemm_core<3, 128, 128, 256, 512, 0, 2, 4>(sm, b - 512, Xp + NL * 512, NL * 256, W + 524288,
                                              Hp + NL * 1024, NL * 512, 0, 0.0625f);
  } else {               // l2: P=5, 64x128, K=128, waves 2x4 (32x32/wave)
    gemm_core<5, 64, 128, 128, 256, 0, 2, 4>(sm, b - 1536, Xp + NL * 1280, NL * 128, W + 655360,
                                             Hp + NL * 2560, NL * 256, 0, 0.08838834765f);
  }
}

__global__ __launch_bounds__(512, 2) void fat2_kernel(
    const unsigned short* __restrict__ Hp, const unsigned short* __restrict__ W,
    float* __restrict__ out) {
  extern __shared__ unsigned short sm[];
  int b = blockIdx.x;
  if (b < 256) {        // l0: 256x256, K=1024
    gemm_core<1, 256, 256, 1024, 512, 1, 2, 4>(sm, b, Hp, 0, W + 688128, out, 0, 0, 0.03125f);
  } else if (b < 768) { // l1: P=3, 128x128, K=512
    gemm_core<3, 128, 128, 512, 256, 1, 2, 4>(sm, b - 256, Hp + NL * 1024, NL * 512, W + 1212416,
                                              out, 0, 512, 0.04419417382f);
  } else {              // l2: P=5, 64x128, K=256
    gemm_core<5, 64, 128, 256, 128, 1, 2, 4>(sm, b - 768, Hp + NL * 2560, NL * 256, W + 1343488,
                                             out, 0, 1280, 0.0625f);
  }
}

extern "C" void kernel_launch(void* const* d_in, const int* in_sizes, int n_in,
                              void* d_out, int out_size, void* d_ws, size_t ws_size,
                              hipStream_t stream) {
  const float* x = (const float*)d_in[0];
  const float* w1_0 = (const float*)d_in[1];
  const float* w1_1 = (const float*)d_in[2];
  const float* w1_2 = (const float*)d_in[3];
  const float* w2_0 = (const float*)d_in[4];
  const float* w2_1 = (const float*)d_in[5];
  const float* w2_2 = (const float*)d_in[6];
  float* out = (float*)d_out;

  unsigned short* Xp = (unsigned short*)d_ws;      // N*1920 bf16
  unsigned short* Hp = Xp + NL * 1920;             // N*3840 bf16
  unsigned short* W  = Hp + NL * 3840;             // 1376256 bf16 (all Wt blocks)

  {
    long total = NL * 896 + 1376256;
    prep_kernel<<<dim3((unsigned)((total + 255) / 256)), dim3(256), 0, stream>>>(
        x, w1_0, w1_1, w1_2, w2_0, w2_1, w2_2, Xp, W);
  }

  // LDS: l0 core 3 x (256+256)*32*2B = 96 KiB (max across branches)
  fat1_kernel<<<2560, 512, 98304, stream>>>(Xp, W, Hp);
  fat2_kernel<<<1280, 512, 98304, stream>>>(Hp, W, out);
}